// Round 2
// baseline (1502.617 us; speedup 1.0000x reference)
//
#include <hip/hip_runtime.h>
#include <hip/hip_bf16.h>
#include <math.h>

#define BB 4
#define NDET 128
#define NT 2048
#define NY 256
#define NX 256
#define DD 256
#define LL 6
#define NHH 8
#define PSS 16
#define NTOK 256
#define MROWS 1024

__device__ __forceinline__ float gelu_exact(float x) {
  return 0.5f * x * (1.0f + erff(x * 0.70710678118654752f));
}

// ---------------- backprojection: one wave per pixel ----------------
__global__ __launch_bounds__(256) void bp_kernel(
    const float* __restrict__ sino, const float* __restrict__ lut,
    float* __restrict__ bp, float* __restrict__ out_bp)
{
  int wid  = (blockIdx.x * 256 + threadIdx.x) >> 6;   // pixel index 0..65535
  int lane = threadIdx.x & 63;
  const float2* lutp = (const float2*)lut + (size_t)wid * NDET;
  float acc0 = 0.f, acc1 = 0.f, acc2 = 0.f, acc3 = 0.f;
  const float wconst = 6.283185307179586f / (float)(NDET - 1);
#pragma unroll
  for (int it = 0; it < 2; ++it) {
    int d = lane + it * 64;
    float2 la = lutp[d];
    int kf = (int)la.x;
    float alpha = la.y;
    if (kf >= 0 && kf < NT - 1) {
      float ap = 0.5f - 0.5f * cosf(wconst * (float)d);
      float w0 = (1.0f - alpha) * ap, w1 = alpha * ap;
      const float* srow = sino + d * NT + kf;
      acc0 += w0 * srow[0] + w1 * srow[1]; srow += NDET * NT;
      acc1 += w0 * srow[0] + w1 * srow[1]; srow += NDET * NT;
      acc2 += w0 * srow[0] + w1 * srow[1]; srow += NDET * NT;
      acc3 += w0 * srow[0] + w1 * srow[1];
    }
  }
#pragma unroll
  for (int off = 32; off; off >>= 1) {
    acc0 += __shfl_xor(acc0, off);
    acc1 += __shfl_xor(acc1, off);
    acc2 += __shfl_xor(acc2, off);
    acc3 += __shfl_xor(acc3, off);
  }
  if (lane == 0) {
    const float inv = 1.0f / 63.5f;   // apod.sum() analytically = 63.5
    float v0 = acc0 * inv, v1 = acc1 * inv, v2 = acc2 * inv, v3 = acc3 * inv;
    bp[0 * 65536 + wid] = v0; out_bp[0 * 65536 + wid] = v0;
    bp[1 * 65536 + wid] = v1; out_bp[1 * 65536 + wid] = v1;
    bp[2 * 65536 + wid] = v2; out_bp[2 * 65536 + wid] = v2;
    bp[3 * 65536 + wid] = v3; out_bp[3 * 65536 + wid] = v3;
  }
}

// ---------------- patchify: bp (B,256,256) -> x (B*256 tokens, 256) -------
__global__ __launch_bounds__(256) void patchify_kernel(
    const float* __restrict__ bp, float* __restrict__ xp)
{
  int gid = blockIdx.x * 256 + threadIdx.x;   // 0..262143
  int m = gid >> 8, pidx = gid & 255;
  int b = m >> 8, n = m & 255;
  int hp = n >> 4, wp = n & 15;
  int i = pidx >> 4, j = pidx & 15;
  xp[gid] = bp[b * 65536 + (hp * 16 + i) * 256 + (wp * 16 + j)];
}

// ---------------- generic fp32 GEMM: C = act(A@W^T + bias) [+ res] --------
// A: (M,K) row-major, W: (N,K) row-major, C: (M,N)
template<int ACT, bool HAS_RES>
__global__ __launch_bounds__(256) void gemm_tn(
    const float* __restrict__ A, const float* __restrict__ W,
    const float* __restrict__ bias, const float* __restrict__ res,
    float* __restrict__ C, int M, int N, int K, int res_rows)
{
  __shared__ float As[16][65];
  __shared__ float Bs[16][65];
  int bm = blockIdx.y * 64, bn = blockIdx.x * 64;
  int tid = threadIdx.x;
  int tx = tid & 15, ty = tid >> 4;
  float acc[4][4] = {{0.f}};
  for (int k0 = 0; k0 < K; k0 += 16) {
#pragma unroll
    for (int j = 0; j < 4; ++j) {
      int li = tid + j * 256;
      int r = li >> 4, k = li & 15;
      As[k][r] = A[(size_t)(bm + r) * K + k0 + k];
      Bs[k][r] = W[(size_t)(bn + r) * K + k0 + k];
    }
    __syncthreads();
#pragma unroll
    for (int k = 0; k < 16; ++k) {
      float a[4], bv[4];
#pragma unroll
      for (int i = 0; i < 4; ++i) a[i] = As[k][ty + 16 * i];
#pragma unroll
      for (int j = 0; j < 4; ++j) bv[j] = Bs[k][tx + 16 * j];
#pragma unroll
      for (int i = 0; i < 4; ++i)
#pragma unroll
        for (int j = 0; j < 4; ++j) acc[i][j] += a[i] * bv[j];
    }
    __syncthreads();
  }
#pragma unroll
  for (int i = 0; i < 4; ++i) {
    int m = bm + ty + 16 * i;
#pragma unroll
    for (int j = 0; j < 4; ++j) {
      int n = bn + tx + 16 * j;
      float c = acc[i][j] + bias[n];
      if (ACT == 1) c = gelu_exact(c);
      if (HAS_RES) c += res[(size_t)(m % res_rows) * N + n];
      C[(size_t)m * N + n] = c;
    }
  }
}

// ---------------- layernorm: one wave (64 threads) per row, D=256 ---------
__global__ __launch_bounds__(64) void ln_kernel(
    const float* __restrict__ x, const float* __restrict__ g,
    const float* __restrict__ b, float* __restrict__ y)
{
  int row = blockIdx.x;
  int l = threadIdx.x;
  const float* xr = x + (size_t)row * DD;
  float v[4];
  float s = 0.f;
#pragma unroll
  for (int j = 0; j < 4; ++j) { v[j] = xr[l + 64 * j]; s += v[j]; }
#pragma unroll
  for (int off = 32; off; off >>= 1) s += __shfl_xor(s, off);
  float mean = s * (1.0f / 256.0f);
  float q = 0.f;
#pragma unroll
  for (int j = 0; j < 4; ++j) { float d = v[j] - mean; q += d * d; }
#pragma unroll
  for (int off = 32; off; off >>= 1) q += __shfl_xor(q, off);
  float inv = 1.0f / sqrtf(q * (1.0f / 256.0f) + 1e-5f);
  float* yr = y + (size_t)row * DD;
#pragma unroll
  for (int j = 0; j < 4; ++j) {
    int c = l + 64 * j;
    yr[c] = (v[j] - mean) * inv * g[c] + b[c];
  }
}

// ---------------- attention: block = (b, h, 16-row chunk) -----------------
__global__ __launch_bounds__(256) void attn_kernel(
    const float* __restrict__ qkv, float* __restrict__ o)
{
  int bi = blockIdx.x;
  int rc = bi & 15, h = (bi >> 4) & 7, b = bi >> 7;
  __shared__ float Ks[256][33];
  __shared__ float Vs[256][33];
  __shared__ float qs[16][33];
  __shared__ float sc[16][257];
  __shared__ float rinv[16];
  int tid = threadIdx.x;
  const float* base = qkv + (size_t)b * 256 * 768;
  for (int li = tid; li < 256 * 32; li += 256) {
    int m = li >> 5, c = li & 31;
    Ks[m][c] = base[m * 768 + 256 + h * 32 + c];
    Vs[m][c] = base[m * 768 + 512 + h * 32 + c];
  }
  for (int li = tid; li < 16 * 32; li += 256) {
    int r = li >> 5, c = li & 31;
    qs[r][c] = base[(rc * 16 + r) * 768 + h * 32 + c];
  }
  __syncthreads();
  {
    int m = tid;
    for (int r = 0; r < 16; ++r) {
      float s = 0.f;
#pragma unroll
      for (int c = 0; c < 32; ++c) s += qs[r][c] * Ks[m][c];
      sc[r][m] = s * 0.17677669529663687f;  // 1/sqrt(32)
    }
  }
  __syncthreads();
  int wv = tid >> 6, ln = tid & 63;
  for (int r = wv * 4; r < wv * 4 + 4; ++r) {
    float v0[4];
    float mx = -1e30f;
#pragma unroll
    for (int j = 0; j < 4; ++j) { v0[j] = sc[r][ln + 64 * j]; mx = fmaxf(mx, v0[j]); }
#pragma unroll
    for (int off = 32; off; off >>= 1) mx = fmaxf(mx, __shfl_xor(mx, off));
    float ssum = 0.f;
#pragma unroll
    for (int j = 0; j < 4; ++j) { v0[j] = expf(v0[j] - mx); ssum += v0[j]; }
#pragma unroll
    for (int off = 32; off; off >>= 1) ssum += __shfl_xor(ssum, off);
#pragma unroll
    for (int j = 0; j < 4; ++j) sc[r][ln + 64 * j] = v0[j];
    if (ln == 0) rinv[r] = 1.0f / ssum;
  }
  __syncthreads();
  for (int oidx = tid; oidx < 512; oidx += 256) {
    int r = oidx >> 5, c = oidx & 31;
    float s = 0.f;
    for (int m = 0; m < 256; ++m) s += sc[r][m] * Vs[m][c];
    o[((size_t)b * 256 + rc * 16 + r) * 256 + h * 32 + c] = s * rinv[r];
  }
}

// ---------------- unpatchify: pixels (B*256,256) -> img (B,256,256) -------
__global__ __launch_bounds__(256) void unpatchify_kernel(
    const float* __restrict__ pix, float* __restrict__ img)
{
  int gid = blockIdx.x * 256 + threadIdx.x;   // 0..262143
  int b = gid >> 16, rem = gid & 65535;
  int yy = rem >> 8, xx = rem & 255;
  int hp = yy >> 4, i = yy & 15;
  int wp = xx >> 4, j = xx & 15;
  img[gid] = pix[((size_t)(b * 256 + hp * 16 + wp)) * 256 + i * 16 + j];
}

// ---------------- conv 3x3 SAME + conv_b + bp residual --------------------
__global__ __launch_bounds__(256) void conv_kernel(
    const float* __restrict__ img, const float* __restrict__ cw,
    const float* __restrict__ cb, const float* __restrict__ bp,
    float* __restrict__ out_img)
{
  int gid = blockIdx.x * 256 + threadIdx.x;
  int b = gid >> 16, rem = gid & 65535;
  int y = rem >> 8, x = rem & 255;
  const float* ip = img + (size_t)b * 65536;
  float s = cb[0];
#pragma unroll
  for (int dy = -1; dy <= 1; ++dy)
#pragma unroll
    for (int dx = -1; dx <= 1; ++dx) {
      int yy = y + dy, xx = x + dx;
      if (yy >= 0 && yy < 256 && xx >= 0 && xx < 256)
        s += cw[(dy + 1) * 3 + (dx + 1)] * ip[yy * 256 + xx];
    }
  out_img[gid] = s + bp[gid];
}

extern "C" void kernel_launch(void* const* d_in, const int* in_sizes, int n_in,
                              void* d_out, int out_size, void* d_ws, size_t ws_size,
                              hipStream_t stream) {
  const float* sino    = (const float*)d_in[0];
  const float* lut     = (const float*)d_in[1];
  const float* patch_w = (const float*)d_in[2];
  const float* patch_b = (const float*)d_in[3];
  const float* pos     = (const float*)d_in[4];
  const float* ln1_g   = (const float*)d_in[5];
  const float* ln1_b   = (const float*)d_in[6];
  const float* wqkv    = (const float*)d_in[7];
  const float* bqkv    = (const float*)d_in[8];
  const float* wo      = (const float*)d_in[9];
  const float* bo      = (const float*)d_in[10];
  const float* ln2_g   = (const float*)d_in[11];
  const float* ln2_b   = (const float*)d_in[12];
  const float* w1      = (const float*)d_in[13];
  const float* b1      = (const float*)d_in[14];
  const float* w2      = (const float*)d_in[15];
  const float* b2      = (const float*)d_in[16];
  const float* proj_w  = (const float*)d_in[17];
  const float* proj_b  = (const float*)d_in[18];
  const float* conv_w  = (const float*)d_in[19];
  const float* conv_b  = (const float*)d_in[20];
  float* out = (float*)d_out;
  float* ws  = (float*)d_ws;

  float* bpb  = ws;                  // 262144
  float* z    = bpb  + 262144;       // 262144
  float* y    = z    + 262144;       // 262144
  float* qkvb = y    + 262144;       // 786432
  float* ob   = qkvb + 786432;       // 262144
  float* hb   = ob   + 262144;       // 1048576
  float* xp   = hb   + 1048576;      // 262144
  float* pixb = xp   + 262144;       // 262144
  float* imgp = pixb + 262144;       // 262144

  // 1. backprojection (also writes bp_img output)
  bp_kernel<<<16384, 256, 0, stream>>>(sino, lut, bpb, out + 262144);

  // 2. patchify + patch embed + pos_embed
  patchify_kernel<<<1024, 256, 0, stream>>>(bpb, xp);
  gemm_tn<0, true><<<dim3(4, 16), 256, 0, stream>>>(
      xp, patch_w, patch_b, pos, z, MROWS, 256, 256, 256);

  // 3. transformer layers
  for (int l = 0; l < LL; ++l) {
    ln_kernel<<<MROWS, 64, 0, stream>>>(z, ln1_g + l * 256, ln1_b + l * 256, y);
    gemm_tn<0, false><<<dim3(12, 16), 256, 0, stream>>>(
        y, wqkv + (size_t)l * 768 * 256, bqkv + l * 768, nullptr, qkvb,
        MROWS, 768, 256, 0);
    attn_kernel<<<512, 256, 0, stream>>>(qkvb, ob);
    gemm_tn<0, true><<<dim3(4, 16), 256, 0, stream>>>(
        ob, wo + (size_t)l * 65536, bo + l * 256, z, z, MROWS, 256, 256, MROWS);
    ln_kernel<<<MROWS, 64, 0, stream>>>(z, ln2_g + l * 256, ln2_b + l * 256, y);
    gemm_tn<1, false><<<dim3(16, 16), 256, 0, stream>>>(
        y, w1 + (size_t)l * 1024 * 256, b1 + l * 1024, nullptr, hb,
        MROWS, 1024, 256, 0);
    gemm_tn<0, true><<<dim3(4, 16), 256, 0, stream>>>(
        hb, w2 + (size_t)l * 256 * 1024, b2 + l * 256, z, z, MROWS, 256, 1024, MROWS);
  }

  // 4. project to pixels, unpatchify, conv + residual
  gemm_tn<0, false><<<dim3(4, 16), 256, 0, stream>>>(
      z, proj_w, proj_b, nullptr, pixb, MROWS, 256, 256, 0);
  unpatchify_kernel<<<1024, 256, 0, stream>>>(pixb, imgp);
  conv_kernel<<<1024, 256, 0, stream>>>(imgp, conv_w, conv_b, bpb, out);
}

// Round 3
// 666.487 us; speedup vs baseline: 2.2545x; 2.2545x over previous
//
#include <hip/hip_runtime.h>
#include <hip/hip_bf16.h>
#include <math.h>

#define BB 4
#define NDET 128
#define NT 2048
#define DD 256
#define LL 6
#define MROWS 1024

typedef __attribute__((ext_vector_type(8))) short s8v;
typedef __attribute__((ext_vector_type(4))) float f32x4;

__device__ __forceinline__ unsigned short f2b(float x) {
  union { float f; unsigned u; } v; v.f = x;
  unsigned r = v.u + 0x7fff + ((v.u >> 16) & 1);
  return (unsigned short)(r >> 16);
}
__device__ __forceinline__ unsigned pk2(float a, float b) {
  return (unsigned)f2b(a) | ((unsigned)f2b(b) << 16);
}
__device__ __forceinline__ float gelu_exact(float x) {
  return 0.5f * x * (1.0f + erff(x * 0.70710678118654752f));
}

// ---------------- fp32 -> bf16 weight cast ----------------
__global__ __launch_bounds__(256) void f2bf_kernel(
    const float* __restrict__ src, unsigned short* __restrict__ dst, int n4)
{
  int i = blockIdx.x * 256 + threadIdx.x;
  int stride = gridDim.x * 256;
  for (; i < n4; i += stride) {
    float4 f = ((const float4*)src)[i];
    uint2 uv;
    uv.x = pk2(f.x, f.y);
    uv.y = pk2(f.z, f.w);
    ((uint2*)dst)[i] = uv;
  }
}

// ---------------- backprojection: thread = pixel, d-outer ----------------
__global__ __launch_bounds__(256) void bp_kernel2(
    const float* __restrict__ sino, const float* __restrict__ lut,
    float* __restrict__ bp, float* __restrict__ out_bp)
{
  __shared__ float apod[NDET];
  int tid = threadIdx.x;
  if (tid < NDET) {
    float ap = 0.5f - 0.5f * cosf(6.283185307179586f * (float)tid / 127.0f);
    apod[tid] = ap * (1.0f / 63.5f);
  }
  __syncthreads();
  int pix = blockIdx.x * 256 + tid;
  const float* lrow = lut + (size_t)pix * 256;  // 128 x float2
  float acc[4] = {0.f, 0.f, 0.f, 0.f};
  for (int d0 = 0; d0 < NDET; d0 += 4) {
    float4 l0 = *(const float4*)(lrow + d0 * 2);
    float4 l1 = *(const float4*)(lrow + d0 * 2 + 4);
    float kfs[4] = {l0.x, l0.z, l1.x, l1.z};
    float als[4] = {l0.y, l0.w, l1.y, l1.w};
#pragma unroll
    for (int dd = 0; dd < 4; ++dd) {
      int kf = (int)kfs[dd];
      if (kf >= 0 && kf < NT - 1) {
        float al = als[dd];
        float ap = apod[d0 + dd];
        float w0 = (1.0f - al) * ap, w1 = al * ap;
        const float* srow = sino + (d0 + dd) * NT + kf;
#pragma unroll
        for (int b = 0; b < 4; ++b)
          acc[b] += w0 * srow[b * NDET * NT] + w1 * srow[b * NDET * NT + 1];
      }
    }
  }
#pragma unroll
  for (int b = 0; b < 4; ++b) {
    bp[b * 65536 + pix] = acc[b];
    out_bp[b * 65536 + pix] = acc[b];
  }
}

// ---------------- bf16 MFMA GEMM: C = act(A@Wb^T + bias) [+res] ----------
// A fp32 (M,K) (AMODE=1: gather from bp image), Wb bf16 (N,K), C fp32 (M,N)
// OMODE=1: scatter C into (B,256,256) image layout (proj+unpatchify).
template<int ACT, int RES, int AMODE, int OMODE>
__global__ __launch_bounds__(256) void gemm_mfma(
    const float* __restrict__ A, const unsigned short* __restrict__ Wb,
    const float* __restrict__ bias, const float* __restrict__ res,
    float* __restrict__ C, int M, int N, int K, int res_mask)
{
  __shared__ __align__(16) unsigned short As[64][40];
  __shared__ __align__(16) unsigned short Bs[64][40];
  int bm = blockIdx.y * 64, bn = blockIdx.x * 64;
  int tid = threadIdx.x;
  int lane = tid & 63, w = tid >> 6;
  int wm = (w >> 1) * 32, wn = (w & 1) * 32;
  f32x4 acc[2][2];
#pragma unroll
  for (int i = 0; i < 2; ++i)
#pragma unroll
    for (int j = 0; j < 2; ++j) acc[i][j] = (f32x4){0.f, 0.f, 0.f, 0.f};

  int sr = tid >> 2, sc = (tid & 3) * 8;
  int lr = lane & 15, lk = (lane >> 4) * 8;

  for (int k0 = 0; k0 < K; k0 += 32) {
    float4 fa0, fa1;
    if (AMODE == 0) {
      const float* ap = A + (size_t)(bm + sr) * K + k0 + sc;
      fa0 = *(const float4*)ap;
      fa1 = *(const float4*)(ap + 4);
    } else {
      int m = bm + sr;
      int bb = m >> 8, nn = m & 255;
      int k = k0 + sc;
      int ii = k >> 4, jj = k & 15;
      const float* ap = A + (size_t)bb * 65536 +
                        ((nn >> 4) * 16 + ii) * 256 + (nn & 15) * 16 + jj;
      fa0 = *(const float4*)ap;
      fa1 = *(const float4*)(ap + 4);
    }
    uint4 ua;
    ua.x = pk2(fa0.x, fa0.y); ua.y = pk2(fa0.z, fa0.w);
    ua.z = pk2(fa1.x, fa1.y); ua.w = pk2(fa1.z, fa1.w);
    *(uint4*)&As[sr][sc] = ua;
    *(uint4*)&Bs[sr][sc] =
        *(const uint4*)(Wb + (size_t)(bn + sr) * K + k0 + sc);
    __syncthreads();

    s8v af0 = *(const s8v*)&As[wm + lr][lk];
    s8v af1 = *(const s8v*)&As[wm + 16 + lr][lk];
    s8v bf0 = *(const s8v*)&Bs[wn + lr][lk];
    s8v bf1 = *(const s8v*)&Bs[wn + 16 + lr][lk];
    acc[0][0] = __builtin_amdgcn_mfma_f32_16x16x32_bf16(af0, bf0, acc[0][0], 0, 0, 0);
    acc[0][1] = __builtin_amdgcn_mfma_f32_16x16x32_bf16(af0, bf1, acc[0][1], 0, 0, 0);
    acc[1][0] = __builtin_amdgcn_mfma_f32_16x16x32_bf16(af1, bf0, acc[1][0], 0, 0, 0);
    acc[1][1] = __builtin_amdgcn_mfma_f32_16x16x32_bf16(af1, bf1, acc[1][1], 0, 0, 0);
    __syncthreads();
  }

  int lg = (lane >> 4) * 4;
#pragma unroll
  for (int i = 0; i < 2; ++i)
#pragma unroll
    for (int j = 0; j < 2; ++j) {
      int n = bn + wn + j * 16 + lr;
      float bv = bias[n];
#pragma unroll
      for (int r4 = 0; r4 < 4; ++r4) {
        int m = bm + wm + i * 16 + lg + r4;
        float c = acc[i][j][r4] + bv;
        if (ACT == 1) c = gelu_exact(c);
        if (RES == 1) c += res[(size_t)(m & res_mask) * N + n];
        if (OMODE == 0) {
          C[(size_t)m * N + n] = c;
        } else {
          int bb = m >> 8, t2 = m & 255;
          C[(size_t)bb * 65536 + ((t2 >> 4) * 16 + (n >> 4)) * 256 +
            (t2 & 15) * 16 + (n & 15)] = c;
        }
      }
    }
}

// ---------------- layernorm: 4 rows/block, wave per row ----------------
__global__ __launch_bounds__(256) void ln_kernel(
    const float* __restrict__ x, const float* __restrict__ g,
    const float* __restrict__ b, float* __restrict__ y)
{
  int row = blockIdx.x * 4 + (threadIdx.x >> 6);
  int l = threadIdx.x & 63;
  const float* xr = x + (size_t)row * DD;
  float v[4];
  float s = 0.f;
#pragma unroll
  for (int j = 0; j < 4; ++j) { v[j] = xr[l + 64 * j]; s += v[j]; }
#pragma unroll
  for (int off = 32; off; off >>= 1) s += __shfl_xor(s, off);
  float mean = s * (1.0f / 256.0f);
  float q = 0.f;
#pragma unroll
  for (int j = 0; j < 4; ++j) { float d = v[j] - mean; q += d * d; }
#pragma unroll
  for (int off = 32; off; off >>= 1) q += __shfl_xor(q, off);
  float inv = 1.0f / sqrtf(q * (1.0f / 256.0f) + 1e-5f);
  float* yr = y + (size_t)row * DD;
#pragma unroll
  for (int j = 0; j < 4; ++j) {
    int c = l + 64 * j;
    yr[c] = (v[j] - mean) * inv * g[c] + b[c];
  }
}

// ---------------- attention 1: S = QK^T/sqrt(d), softmax -> P (bf16) ------
// grid: 256 = (b,h,qc); block 256 thr / 4 waves; wave w covers cols w*64..+63
__global__ __launch_bounds__(256) void attn_qk(
    const float* __restrict__ qkv, unsigned short* __restrict__ Pg)
{
  __shared__ __align__(16) unsigned short Kl[256][40];
  __shared__ __align__(16) unsigned short Qb[32][40];
  __shared__ __align__(16) float Sf[32][264];
  int bi = blockIdx.x;
  int qc = bi & 7, h = (bi >> 3) & 7, b = bi >> 6;
  int tid = threadIdx.x, lane = tid & 63, w = tid >> 6;
  const float* base = qkv + (size_t)b * 256 * 768;

  {  // stage K row `tid`
    const float* kr = base + tid * 768 + 256 + h * 32;
#pragma unroll
    for (int c = 0; c < 32; c += 8) {
      float4 f0 = *(const float4*)(kr + c);
      float4 f1 = *(const float4*)(kr + c + 4);
      uint4 u;
      u.x = pk2(f0.x, f0.y); u.y = pk2(f0.z, f0.w);
      u.z = pk2(f1.x, f1.y); u.w = pk2(f1.z, f1.w);
      *(uint4*)&Kl[tid][c] = u;
    }
    int row = tid >> 3, c0 = (tid & 7) * 4;
    float4 f = *(const float4*)(base + (qc * 32 + row) * 768 + h * 32 + c0);
    uint2 u2; u2.x = pk2(f.x, f.y); u2.y = pk2(f.z, f.w);
    *(uint2*)&Qb[row][c0] = u2;
  }
  __syncthreads();

  int lr = lane & 15, lk = (lane >> 4) * 8, lg = (lane >> 4) * 4;
  {
    s8v qa0 = *(const s8v*)&Qb[lr][lk];
    s8v qa1 = *(const s8v*)&Qb[16 + lr][lk];
    f32x4 z4 = (f32x4){0.f, 0.f, 0.f, 0.f};
#pragma unroll
    for (int j = 0; j < 4; ++j) {
      s8v kb = *(const s8v*)&Kl[w * 64 + j * 16 + lr][lk];
      f32x4 s0 = __builtin_amdgcn_mfma_f32_16x16x32_bf16(qa0, kb, z4, 0, 0, 0);
      f32x4 s1 = __builtin_amdgcn_mfma_f32_16x16x32_bf16(qa1, kb, z4, 0, 0, 0);
#pragma unroll
      for (int r4 = 0; r4 < 4; ++r4) {
        Sf[lg + r4][w * 64 + j * 16 + lr] = s0[r4];
        Sf[16 + lg + r4][w * 64 + j * 16 + lr] = s1[r4];
      }
    }
  }
  __syncthreads();

  // softmax: wave w handles rows w*8 .. w*8+7, 4 cols/lane
  const float scale = 0.17677669529663687f;
  for (int rr = 0; rr < 8; ++rr) {
    int row = w * 8 + rr;
    float4 v = *(const float4*)&Sf[row][lane * 4];
    v.x *= scale; v.y *= scale; v.z *= scale; v.w *= scale;
    float mx = fmaxf(fmaxf(v.x, v.y), fmaxf(v.z, v.w));
#pragma unroll
    for (int off = 32; off; off >>= 1) mx = fmaxf(mx, __shfl_xor(mx, off));
    float e0 = expf(v.x - mx), e1 = expf(v.y - mx);
    float e2 = expf(v.z - mx), e3 = expf(v.w - mx);
    float ss = e0 + e1 + e2 + e3;
#pragma unroll
    for (int off = 32; off; off >>= 1) ss += __shfl_xor(ss, off);
    float inv = 1.0f / ss;
    uint2 u2;
    u2.x = pk2(e0 * inv, e1 * inv);
    u2.y = pk2(e2 * inv, e3 * inv);
    size_t off0 = ((size_t)((b * 8 + h) * 256) + qc * 32 + row) * 256 + lane * 4;
    *(uint2*)&Pg[off0] = u2;
  }
}

// ---------------- attention 2: O = P @ V ----------------
__global__ __launch_bounds__(256) void attn_pv(
    const float* __restrict__ qkv, const unsigned short* __restrict__ Pg,
    float* __restrict__ o)
{
  __shared__ __align__(16) unsigned short Vt[32][264];
  __shared__ __align__(16) float Op[4][32][33];
  int bi = blockIdx.x;
  int qc = bi & 7, h = (bi >> 3) & 7, b = bi >> 6;
  int tid = threadIdx.x, lane = tid & 63, w = tid >> 6;
  const float* base = qkv + (size_t)b * 256 * 768;

  {  // stage V row `tid`, transposed
    const float* vr = base + tid * 768 + 512 + h * 32;
#pragma unroll
    for (int c = 0; c < 32; c += 4) {
      float4 f = *(const float4*)(vr + c);
      Vt[c][tid] = f2b(f.x);
      Vt[c + 1][tid] = f2b(f.y);
      Vt[c + 2][tid] = f2b(f.z);
      Vt[c + 3][tid] = f2b(f.w);
    }
  }
  __syncthreads();

  int lr = lane & 15, lk = (lane >> 4) * 8, lg = (lane >> 4) * 4;
  f32x4 oacc[2][2];
#pragma unroll
  for (int i = 0; i < 2; ++i)
#pragma unroll
    for (int j = 0; j < 2; ++j) oacc[i][j] = (f32x4){0.f, 0.f, 0.f, 0.f};

  size_t prow = ((size_t)((b * 8 + h) * 256) + qc * 32);
#pragma unroll
  for (int s = 0; s < 2; ++s) {
    int m0 = w * 64 + s * 32;
    s8v pa0 = *(const s8v*)&Pg[(prow + lr) * 256 + m0 + lk];
    s8v pa1 = *(const s8v*)&Pg[(prow + 16 + lr) * 256 + m0 + lk];
    s8v vb0 = *(const s8v*)&Vt[lr][m0 + lk];
    s8v vb1 = *(const s8v*)&Vt[16 + lr][m0 + lk];
    oacc[0][0] = __builtin_amdgcn_mfma_f32_16x16x32_bf16(pa0, vb0, oacc[0][0], 0, 0, 0);
    oacc[0][1] = __builtin_amdgcn_mfma_f32_16x16x32_bf16(pa0, vb1, oacc[0][1], 0, 0, 0);
    oacc[1][0] = __builtin_amdgcn_mfma_f32_16x16x32_bf16(pa1, vb0, oacc[1][0], 0, 0, 0);
    oacc[1][1] = __builtin_amdgcn_mfma_f32_16x16x32_bf16(pa1, vb1, oacc[1][1], 0, 0, 0);
  }
#pragma unroll
  for (int i = 0; i < 2; ++i)
#pragma unroll
    for (int j = 0; j < 2; ++j)
#pragma unroll
      for (int r4 = 0; r4 < 4; ++r4)
        Op[w][i * 16 + lg + r4][j * 16 + lr] = oacc[i][j][r4];
  __syncthreads();

#pragma unroll
  for (int k = 0; k < 4; ++k) {
    int idx = tid + k * 256;
    int q = idx >> 5, d = idx & 31;
    float s = Op[0][q][d] + Op[1][q][d] + Op[2][q][d] + Op[3][q][d];
    o[((size_t)(b * 256) + qc * 32 + q) * 256 + h * 32 + d] = s;
  }
}

// ---------------- conv 3x3 SAME + conv_b + bp residual --------------------
__global__ __launch_bounds__(256) void conv_kernel(
    const float* __restrict__ img, const float* __restrict__ cw,
    const float* __restrict__ cb, const float* __restrict__ bp,
    float* __restrict__ out_img)
{
  int gid = blockIdx.x * 256 + threadIdx.x;
  int b = gid >> 16, rem = gid & 65535;
  int y = rem >> 8, x = rem & 255;
  const float* ip = img + (size_t)b * 65536;
  float s = cb[0];
#pragma unroll
  for (int dy = -1; dy <= 1; ++dy)
#pragma unroll
    for (int dx = -1; dx <= 1; ++dx) {
      int yy = y + dy, xx = x + dx;
      if (yy >= 0 && yy < 256 && xx >= 0 && xx < 256)
        s += cw[(dy + 1) * 3 + (dx + 1)] * ip[yy * 256 + xx];
    }
  out_img[gid] = s + bp[gid];
}

extern "C" void kernel_launch(void* const* d_in, const int* in_sizes, int n_in,
                              void* d_out, int out_size, void* d_ws, size_t ws_size,
                              hipStream_t stream) {
  const float* sino    = (const float*)d_in[0];
  const float* lut     = (const float*)d_in[1];
  const float* patch_w = (const float*)d_in[2];
  const float* patch_b = (const float*)d_in[3];
  const float* pos     = (const float*)d_in[4];
  const float* ln1_g   = (const float*)d_in[5];
  const float* ln1_b   = (const float*)d_in[6];
  const float* wqkv    = (const float*)d_in[7];
  const float* bqkv    = (const float*)d_in[8];
  const float* wo      = (const float*)d_in[9];
  const float* bo      = (const float*)d_in[10];
  const float* ln2_g   = (const float*)d_in[11];
  const float* ln2_b   = (const float*)d_in[12];
  const float* w1      = (const float*)d_in[13];
  const float* b1      = (const float*)d_in[14];
  const float* w2      = (const float*)d_in[15];
  const float* b2      = (const float*)d_in[16];
  const float* proj_w  = (const float*)d_in[17];
  const float* proj_b  = (const float*)d_in[18];
  const float* conv_w  = (const float*)d_in[19];
  const float* conv_b  = (const float*)d_in[20];
  float* out = (float*)d_out;
  float* ws  = (float*)d_ws;

  // fp32 scratch
  float* bpb  = ws;                  // 262144
  float* z    = bpb  + 262144;
  float* y    = z    + 262144;
  float* qkvb = y    + 262144;       // 786432
  float* ob   = qkvb + 786432;       // 262144
  float* hb   = ob   + 262144;       // 1048576
  float* imgp = hb   + 1048576;      // 262144
  // bf16 region (after 3145728 floats)
  unsigned short* wsu   = (unsigned short*)(ws + 3145728);
  unsigned short* pwb   = wsu;                       // 65536
  unsigned short* qkvw  = pwb  + 65536;              // 1179648
  unsigned short* wow   = qkvw + 1179648;            // 393216
  unsigned short* w1w   = wow  + 393216;             // 1572864
  unsigned short* w2w   = w1w  + 1572864;            // 1572864
  unsigned short* projw = w2w  + 1572864;            // 65536
  unsigned short* Pg    = projw + 65536;             // 8388608 (P bf16)

  // weight casts
  f2bf_kernel<<<512, 256, 0, stream>>>(patch_w, pwb, 65536 / 4);
  f2bf_kernel<<<512, 256, 0, stream>>>(wqkv, qkvw, 1179648 / 4);
  f2bf_kernel<<<512, 256, 0, stream>>>(wo, wow, 393216 / 4);
  f2bf_kernel<<<512, 256, 0, stream>>>(w1, w1w, 1572864 / 4);
  f2bf_kernel<<<512, 256, 0, stream>>>(w2, w2w, 1572864 / 4);
  f2bf_kernel<<<512, 256, 0, stream>>>(proj_w, projw, 65536 / 4);

  // backprojection (also writes bp_img output)
  bp_kernel2<<<256, 256, 0, stream>>>(sino, lut, bpb, out + 262144);

  // patch embed (patchify fused) + pos
  gemm_mfma<0, 1, 1, 0><<<dim3(4, 16), 256, 0, stream>>>(
      bpb, pwb, patch_b, pos, z, MROWS, 256, 256, 255);

  for (int l = 0; l < LL; ++l) {
    ln_kernel<<<256, 256, 0, stream>>>(z, ln1_g + l * 256, ln1_b + l * 256, y);
    gemm_mfma<0, 0, 0, 0><<<dim3(12, 16), 256, 0, stream>>>(
        y, qkvw + (size_t)l * 196608, bqkv + l * 768, nullptr, qkvb,
        MROWS, 768, 256, 0);
    attn_qk<<<256, 256, 0, stream>>>(qkvb, Pg);
    attn_pv<<<256, 256, 0, stream>>>(qkvb, Pg, ob);
    gemm_mfma<0, 1, 0, 0><<<dim3(4, 16), 256, 0, stream>>>(
        ob, wow + (size_t)l * 65536, bo + l * 256, z, z, MROWS, 256, 256, 1023);
    ln_kernel<<<256, 256, 0, stream>>>(z, ln2_g + l * 256, ln2_b + l * 256, y);
    gemm_mfma<1, 0, 0, 0><<<dim3(16, 16), 256, 0, stream>>>(
        y, w1w + (size_t)l * 262144, b1 + l * 1024, nullptr, hb,
        MROWS, 1024, 256, 0);
    gemm_mfma<0, 1, 0, 0><<<dim3(4, 16), 256, 0, stream>>>(
        hb, w2w + (size_t)l * 262144, b2 + l * 256, z, z, MROWS, 256, 1024, 1023);
  }

  // proj -> pixels scattered directly into image layout, then conv+residual
  gemm_mfma<0, 0, 0, 1><<<dim3(4, 16), 256, 0, stream>>>(
      z, projw, proj_b, nullptr, imgp, MROWS, 256, 256, 0);
  conv_kernel<<<1024, 256, 0, stream>>>(imgp, conv_w, conv_b, bpb, out);
}

// Round 4
// 522.753 us; speedup vs baseline: 2.8744x; 1.2750x over previous
//
#include <hip/hip_runtime.h>
#include <hip/hip_bf16.h>
#include <math.h>

#define BB 4
#define NDET 128
#define NT 2048
#define DD 256
#define LL 6
#define MROWS 1024

typedef __attribute__((ext_vector_type(8))) short s8v;
typedef __attribute__((ext_vector_type(4))) float f32x4;
typedef unsigned short ushort_t;

__device__ __forceinline__ unsigned short f2b(float x) {
  union { float f; unsigned u; } v; v.f = x;
  unsigned r = v.u + 0x7fff + ((v.u >> 16) & 1);
  return (unsigned short)(r >> 16);
}
__device__ __forceinline__ unsigned pk2(float a, float b) {
  return (unsigned)f2b(a) | ((unsigned)f2b(b) << 16);
}
__device__ __forceinline__ float gelu_exact(float x) {
  return 0.5f * x * (1.0f + erff(x * 0.70710678118654752f));
}

// ---------------- merged fp32 -> bf16 weight cast (6 tensors) -------------
__global__ __launch_bounds__(256) void cast_all(
    const float* __restrict__ s0, const float* __restrict__ s1,
    const float* __restrict__ s2, const float* __restrict__ s3,
    const float* __restrict__ s4, const float* __restrict__ s5,
    unsigned short* __restrict__ d0, unsigned short* __restrict__ d1,
    unsigned short* __restrict__ d2, unsigned short* __restrict__ d3,
    unsigned short* __restrict__ d4, unsigned short* __restrict__ d5)
{
  // cumulative float4 counts
  const int e0 = 16384, e1 = 311296, e2 = 409600, e3 = 802816, e4 = 1196032,
            e5 = 1212416;
  int i = blockIdx.x * 256 + threadIdx.x;
  int stride = gridDim.x * 256;
  for (; i < e5; i += stride) {
    const float* s; unsigned short* d; int j;
    if (i < e0)      { s = s0; d = d0; j = i; }
    else if (i < e1) { s = s1; d = d1; j = i - e0; }
    else if (i < e2) { s = s2; d = d2; j = i - e1; }
    else if (i < e3) { s = s3; d = d3; j = i - e2; }
    else if (i < e4) { s = s4; d = d4; j = i - e3; }
    else             { s = s5; d = d5; j = i - e4; }
    float4 f = ((const float4*)s)[j];
    uint2 uv;
    uv.x = pk2(f.x, f.y);
    uv.y = pk2(f.z, f.w);
    ((uint2*)d)[j] = uv;
  }
}

// ---------------- backprojection part: 8 detector chunks ------------------
__global__ __launch_bounds__(256) void bp_part(
    const float* __restrict__ sino, const float* __restrict__ lut,
    float* __restrict__ partial)
{
  __shared__ float apod[NDET];
  int tid = threadIdx.x;
  if (tid < NDET) {
    float ap = 0.5f - 0.5f * cosf(6.283185307179586f * (float)tid / 127.0f);
    apod[tid] = ap * (1.0f / 63.5f);
  }
  __syncthreads();
  int c = blockIdx.x >> 8;          // detector chunk 0..7
  int pb = blockIdx.x & 255;
  int pix = pb * 256 + tid;
  const float* lrow = lut + (size_t)pix * 256;
  float acc[4] = {0.f, 0.f, 0.f, 0.f};
#pragma unroll
  for (int d0 = c * 16; d0 < c * 16 + 16; d0 += 4) {
    float4 l0 = *(const float4*)(lrow + d0 * 2);
    float4 l1 = *(const float4*)(lrow + d0 * 2 + 4);
    float kfs[4] = {l0.x, l0.z, l1.x, l1.z};
    float als[4] = {l0.y, l0.w, l1.y, l1.w};
#pragma unroll
    for (int dd = 0; dd < 4; ++dd) {
      int kf = (int)kfs[dd];
      if (kf >= 0 && kf < NT - 1) {
        float al = als[dd];
        float ap = apod[d0 + dd];
        float w0 = (1.0f - al) * ap, w1 = al * ap;
        const float* srow = sino + (d0 + dd) * NT + kf;
#pragma unroll
        for (int b = 0; b < 4; ++b)
          acc[b] += w0 * srow[b * NDET * NT] + w1 * srow[b * NDET * NT + 1];
      }
    }
  }
#pragma unroll
  for (int b = 0; b < 4; ++b)
    partial[(size_t)(c * 4 + b) * 65536 + pix] = acc[b];
}

__global__ __launch_bounds__(256) void bp_reduce(
    const float* __restrict__ partial, float* __restrict__ bp,
    float* __restrict__ out_bp)
{
  int pix = blockIdx.x * 256 + threadIdx.x;
#pragma unroll
  for (int b = 0; b < 4; ++b) {
    float s = 0.f;
#pragma unroll
    for (int c = 0; c < 8; ++c) s += partial[(size_t)(c * 4 + b) * 65536 + pix];
    bp[b * 65536 + pix] = s;
    out_bp[b * 65536 + pix] = s;
  }
}

// ---------------- panel-staged bf16 MFMA GEMM -----------------------------
// tile 32(M) x 64(N), full-K panels in LDS (chunks of 256), 4 waves.
// AMODE: 0 = A fp32 row-major, 1 = gather from bp image, 2 = LN(A) fused
// OMODE: 0 = fp32 out, 1 = scatter to image, 2 = bf16 out
template<int ACT, int RES, int AMODE, int OMODE>
__global__ __launch_bounds__(256) void gemm2(
    const float* __restrict__ A, const unsigned short* __restrict__ Wb,
    const float* __restrict__ bias, const float* __restrict__ res,
    const float* __restrict__ lng, const float* __restrict__ lnb,
    float* __restrict__ C, unsigned short* __restrict__ C16,
    int M, int N, int K, int res_mask)
{
  __shared__ __align__(16) unsigned short As[32][264];
  __shared__ __align__(16) unsigned short Bs[64][264];
  int bm = blockIdx.y * 32, bn = blockIdx.x * 64;
  int tid = threadIdx.x;
  int lane = tid & 63, w = tid >> 6;
  int lr = lane & 15, hi = lane >> 4;
  int lk = hi * 8, lg = hi * 4;
  int wr = (w & 1) * 16, wc = (w >> 1) * 32;
  f32x4 acc[2];
  acc[0] = (f32x4){0.f, 0.f, 0.f, 0.f};
  acc[1] = (f32x4){0.f, 0.f, 0.f, 0.f};

  for (int kc = 0; kc < K; kc += 256) {
    if (kc) __syncthreads();
    // ---- stage A panel 32 x 256 ----
    if (AMODE == 2) {
      // layernorm fused: wave w handles rows w*8 .. w*8+7
      float4 gl = ((const float4*)lng)[lane];
      float4 bl = ((const float4*)lnb)[lane];
#pragma unroll
      for (int rr = 0; rr < 8; ++rr) {
        int row = w * 8 + rr;
        float4 v = ((const float4*)(A + (size_t)(bm + row) * 256))[lane];
        float s = v.x + v.y + v.z + v.w;
#pragma unroll
        for (int off = 32; off; off >>= 1) s += __shfl_xor(s, off);
        float mean = s * (1.0f / 256.0f);
        float q = (v.x - mean) * (v.x - mean) + (v.y - mean) * (v.y - mean) +
                  (v.z - mean) * (v.z - mean) + (v.w - mean) * (v.w - mean);
#pragma unroll
        for (int off = 32; off; off >>= 1) q += __shfl_xor(q, off);
        float inv = 1.0f / sqrtf(q * (1.0f / 256.0f) + 1e-5f);
        float y0 = (v.x - mean) * inv * gl.x + bl.x;
        float y1 = (v.y - mean) * inv * gl.y + bl.y;
        float y2 = (v.z - mean) * inv * gl.z + bl.z;
        float y3 = (v.w - mean) * inv * gl.w + bl.w;
        uint2 u2; u2.x = pk2(y0, y1); u2.y = pk2(y2, y3);
        *(uint2*)&As[row][lane * 4] = u2;
      }
    } else {
      int r = tid >> 3, cbase = (tid & 7) * 32;
#pragma unroll
      for (int q8 = 0; q8 < 8; ++q8) {
        int k = cbase + q8 * 4;
        float4 f;
        if (AMODE == 0) {
          f = *(const float4*)(A + (size_t)(bm + r) * K + kc + k);
        } else {
          int m = bm + r;
          int bb = m >> 8, nn = m & 255;
          int ii = k >> 4, jj = k & 15;
          f = *(const float4*)(A + (size_t)bb * 65536 +
                               ((nn >> 4) * 16 + ii) * 256 + (nn & 15) * 16 + jj);
        }
        uint2 u2; u2.x = pk2(f.x, f.y); u2.y = pk2(f.z, f.w);
        *(uint2*)&As[r][k] = u2;
      }
    }
    // ---- stage B panel 64 x 256 ----
    {
      int r = tid >> 2, cbase = (tid & 3) * 64;
      const unsigned short* wp = Wb + (size_t)(bn + r) * K + kc + cbase;
#pragma unroll
      for (int q8 = 0; q8 < 8; ++q8)
        *(uint4*)&Bs[r][cbase + q8 * 8] = *(const uint4*)(wp + q8 * 8);
    }
    __syncthreads();
    // ---- MFMA over the panel ----
#pragma unroll
    for (int k0 = 0; k0 < 256; k0 += 32) {
      s8v a = *(const s8v*)&As[wr + lr][k0 + lk];
      s8v b0 = *(const s8v*)&Bs[wc + lr][k0 + lk];
      s8v b1 = *(const s8v*)&Bs[wc + 16 + lr][k0 + lk];
      acc[0] = __builtin_amdgcn_mfma_f32_16x16x32_bf16(a, b0, acc[0], 0, 0, 0);
      acc[1] = __builtin_amdgcn_mfma_f32_16x16x32_bf16(a, b1, acc[1], 0, 0, 0);
    }
  }

#pragma unroll
  for (int j = 0; j < 2; ++j) {
    int n = bn + wc + j * 16 + lr;
    float bv = bias[n];
#pragma unroll
    for (int r4 = 0; r4 < 4; ++r4) {
      int m = bm + wr + lg + r4;
      float c = acc[j][r4] + bv;
      if (ACT == 1) c = gelu_exact(c);
      if (RES == 1) c += res[(size_t)(m & res_mask) * N + n];
      if (OMODE == 0) {
        C[(size_t)m * N + n] = c;
      } else if (OMODE == 1) {
        int bb = m >> 8, t2 = m & 255;
        C[(size_t)bb * 65536 + ((t2 >> 4) * 16 + (n >> 4)) * 256 +
          (t2 & 15) * 16 + (n & 15)] = c;
      } else {
        C16[(size_t)m * N + n] = f2b(c);
      }
    }
  }
}

// ---------------- fused attention: QK^T + softmax + PV --------------------
// grid 256 = (b, h, qc32); block 256 / 4 waves. qkv is bf16 (1024 x 768).
__global__ __launch_bounds__(256) void attn_fused(
    const unsigned short* __restrict__ qkv, float* __restrict__ o)
{
  __shared__ __align__(16) unsigned short Kl[256][40];
  __shared__ __align__(16) unsigned short Qb[32][40];
  __shared__ __align__(16) unsigned short Vt[32][264];
  __shared__ __align__(16) unsigned short Pl[32][264];
  __shared__ __align__(16) float Sf[32][268];
  int bi = blockIdx.x;
  int qc = bi & 7, h = (bi >> 3) & 7, b = bi >> 6;
  int tid = threadIdx.x, lane = tid & 63, w = tid >> 6;
  int lr = lane & 15, hi = lane >> 4;
  int lk = hi * 8, lg = hi * 4;
  const unsigned short* base = qkv + (size_t)b * 256 * 768;

  {  // stage K row tid, V row tid (transposed), Q rows
    const unsigned short* kr = base + tid * 768 + 256 + h * 32;
#pragma unroll
    for (int cq = 0; cq < 4; ++cq)
      *(uint4*)&Kl[tid][cq * 8] = *(const uint4*)(kr + cq * 8);
    const unsigned short* vr = base + tid * 768 + 512 + h * 32;
    unsigned short tmp[32];
#pragma unroll
    for (int cq = 0; cq < 4; ++cq)
      *(uint4*)&tmp[cq * 8] = *(const uint4*)(vr + cq * 8);
#pragma unroll
    for (int cc = 0; cc < 32; ++cc) Vt[cc][tid] = tmp[cc];
    int row = tid >> 3, c0 = (tid & 7) * 4;
    *(uint2*)&Qb[row][c0] =
        *(const uint2*)(base + (qc * 32 + row) * 768 + h * 32 + c0);
  }
  __syncthreads();

  {  // QK^T: wave w covers score cols w*64 .. w*64+63
    s8v qa0 = *(const s8v*)&Qb[lr][lk];
    s8v qa1 = *(const s8v*)&Qb[16 + lr][lk];
    f32x4 z4 = (f32x4){0.f, 0.f, 0.f, 0.f};
#pragma unroll
    for (int j = 0; j < 4; ++j) {
      s8v kb = *(const s8v*)&Kl[w * 64 + j * 16 + lr][lk];
      f32x4 s0 = __builtin_amdgcn_mfma_f32_16x16x32_bf16(qa0, kb, z4, 0, 0, 0);
      f32x4 s1 = __builtin_amdgcn_mfma_f32_16x16x32_bf16(qa1, kb, z4, 0, 0, 0);
#pragma unroll
      for (int r4 = 0; r4 < 4; ++r4) {
        Sf[lg + r4][w * 64 + j * 16 + lr] = s0[r4];
        Sf[16 + lg + r4][w * 64 + j * 16 + lr] = s1[r4];
      }
    }
  }
  __syncthreads();

  {  // softmax: wave w rows w*8..w*8+7; write P bf16 to LDS
    const float scale = 0.17677669529663687f;
    for (int rr = 0; rr < 8; ++rr) {
      int row = w * 8 + rr;
      float4 v = *(const float4*)&Sf[row][lane * 4];
      v.x *= scale; v.y *= scale; v.z *= scale; v.w *= scale;
      float mx = fmaxf(fmaxf(v.x, v.y), fmaxf(v.z, v.w));
#pragma unroll
      for (int off = 32; off; off >>= 1) mx = fmaxf(mx, __shfl_xor(mx, off));
      float e0 = expf(v.x - mx), e1 = expf(v.y - mx);
      float e2 = expf(v.z - mx), e3 = expf(v.w - mx);
      float ss = e0 + e1 + e2 + e3;
#pragma unroll
      for (int off = 32; off; off >>= 1) ss += __shfl_xor(ss, off);
      float inv = 1.0f / ss;
      uint2 u2;
      u2.x = pk2(e0 * inv, e1 * inv);
      u2.y = pk2(e2 * inv, e3 * inv);
      *(uint2*)&Pl[row][lane * 4] = u2;
    }
  }
  __syncthreads();

  {  // PV: wave w -> rows (w&1)*16, cols (w>>1)*16; full K=256 per wave
    int wr = (w & 1) * 16, wc = (w >> 1) * 16;
    f32x4 oa = (f32x4){0.f, 0.f, 0.f, 0.f};
#pragma unroll
    for (int ks = 0; ks < 8; ++ks) {
      s8v pa = *(const s8v*)&Pl[wr + lr][ks * 32 + lk];
      s8v vb = *(const s8v*)&Vt[wc + lr][ks * 32 + lk];
      oa = __builtin_amdgcn_mfma_f32_16x16x32_bf16(pa, vb, oa, 0, 0, 0);
    }
#pragma unroll
    for (int r4 = 0; r4 < 4; ++r4) {
      int row = qc * 32 + wr + lg + r4;
      o[((size_t)(b * 256) + row) * 256 + h * 32 + wc + lr] = oa[r4];
    }
  }
}

// ---------------- conv 3x3 SAME + conv_b + bp residual --------------------
__global__ __launch_bounds__(256) void conv_kernel(
    const float* __restrict__ img, const float* __restrict__ cw,
    const float* __restrict__ cb, const float* __restrict__ bp,
    float* __restrict__ out_img)
{
  int gid = blockIdx.x * 256 + threadIdx.x;
  int b = gid >> 16, rem = gid & 65535;
  int y = rem >> 8, x = rem & 255;
  const float* ip = img + (size_t)b * 65536;
  float s = cb[0];
#pragma unroll
  for (int dy = -1; dy <= 1; ++dy)
#pragma unroll
    for (int dx = -1; dx <= 1; ++dx) {
      int yy = y + dy, xx = x + dx;
      if (yy >= 0 && yy < 256 && xx >= 0 && xx < 256)
        s += cw[(dy + 1) * 3 + (dx + 1)] * ip[yy * 256 + xx];
    }
  out_img[gid] = s + bp[gid];
}

extern "C" void kernel_launch(void* const* d_in, const int* in_sizes, int n_in,
                              void* d_out, int out_size, void* d_ws, size_t ws_size,
                              hipStream_t stream) {
  const float* sino    = (const float*)d_in[0];
  const float* lut     = (const float*)d_in[1];
  const float* patch_w = (const float*)d_in[2];
  const float* patch_b = (const float*)d_in[3];
  const float* pos     = (const float*)d_in[4];
  const float* ln1_g   = (const float*)d_in[5];
  const float* ln1_b   = (const float*)d_in[6];
  const float* wqkv    = (const float*)d_in[7];
  const float* bqkv    = (const float*)d_in[8];
  const float* wo      = (const float*)d_in[9];
  const float* bo      = (const float*)d_in[10];
  const float* ln2_g   = (const float*)d_in[11];
  const float* ln2_b   = (const float*)d_in[12];
  const float* w1      = (const float*)d_in[13];
  const float* b1      = (const float*)d_in[14];
  const float* w2      = (const float*)d_in[15];
  const float* b2      = (const float*)d_in[16];
  const float* proj_w  = (const float*)d_in[17];
  const float* proj_b  = (const float*)d_in[18];
  const float* conv_w  = (const float*)d_in[19];
  const float* conv_b  = (const float*)d_in[20];
  float* out = (float*)d_out;
  float* ws  = (float*)d_ws;

  // fp32 scratch
  float* bpb     = ws;                   // 262144
  float* z       = bpb + 262144;         // 262144
  float* ob      = z + 262144;           // 262144
  float* hb      = ob + 262144;          // 1048576
  float* imgp    = hb + 1048576;         // 262144
  float* partial = imgp + 262144;        // 2097152
  // bf16 region
  unsigned short* wsu    = (unsigned short*)(partial + 2097152);
  unsigned short* pwb    = wsu;                 // 65536
  unsigned short* qkvw   = pwb + 65536;         // 1179648
  unsigned short* wow    = qkvw + 1179648;      // 393216
  unsigned short* w1w    = wow + 393216;        // 1572864
  unsigned short* w2w    = w1w + 1572864;       // 1572864
  unsigned short* projw  = w2w + 1572864;       // 65536
  unsigned short* qkvb16 = projw + 65536;       // 786432

  cast_all<<<2048, 256, 0, stream>>>(patch_w, wqkv, wo, w1, w2, proj_w,
                                     pwb, qkvw, wow, w1w, w2w, projw);

  bp_part<<<2048, 256, 0, stream>>>(sino, lut, partial);
  bp_reduce<<<256, 256, 0, stream>>>(partial, bpb, out + 262144);

  // patch embed (gather from image) + pos_embed
  gemm2<0, 1, 1, 0><<<dim3(4, 32), 256, 0, stream>>>(
      bpb, pwb, patch_b, pos, nullptr, nullptr, z, nullptr,
      MROWS, 256, 256, 255);

  for (int l = 0; l < LL; ++l) {
    // LN1 + QKV -> bf16
    gemm2<0, 0, 2, 2><<<dim3(12, 32), 256, 0, stream>>>(
        z, qkvw + (size_t)l * 196608, bqkv + l * 768, nullptr,
        ln1_g + l * 256, ln1_b + l * 256, nullptr, qkvb16,
        MROWS, 768, 256, 0);
    attn_fused<<<256, 256, 0, stream>>>(qkvb16, ob);
    // WO + residual
    gemm2<0, 1, 0, 0><<<dim3(4, 32), 256, 0, stream>>>(
        ob, wow + (size_t)l * 65536, bo + l * 256, z, nullptr, nullptr,
        z, nullptr, MROWS, 256, 256, 1023);
    // LN2 + FC1 + gelu
    gemm2<1, 0, 2, 0><<<dim3(16, 32), 256, 0, stream>>>(
        z, w1w + (size_t)l * 262144, b1 + l * 1024, nullptr,
        ln2_g + l * 256, ln2_b + l * 256, hb, nullptr,
        MROWS, 1024, 256, 0);
    // FC2 + residual
    gemm2<0, 1, 0, 0><<<dim3(4, 32), 256, 0, stream>>>(
        hb, w2w + (size_t)l * 262144, b2 + l * 256, z, nullptr, nullptr,
        z, nullptr, MROWS, 256, 1024, 1023);
  }

  // proj scattered into image layout, then conv + bp residual
  gemm2<0, 0, 0, 1><<<dim3(4, 32), 256, 0, stream>>>(
      z, projw, proj_b, nullptr, nullptr, nullptr, imgp, nullptr,
      MROWS, 256, 256, 0);
  conv_kernel<<<1024, 256, 0, stream>>>(imgp, conv_w, conv_b, bpb, out);
}